// Round 2
// baseline (299.481 us; speedup 1.0000x reference)
//
#include <hip/hip_runtime.h>

// Problem constants (from setup_inputs)
constexpr int B = 2, V = 5, C = 32, H = 256, W = 320, D = 4;
constexpr int HW = H * W;
constexpr int NTHREAD = B * HW;        // 163840 threads, one per (b,h,w)
constexpr int BLK = 128;
constexpr int NBLK = NTHREAD / BLK;    // 1280, divisible by 8 (XCD swizzle OK)

// rot (9) + trans (3) per (b, src view v=1..4), fp32 (bit-exact ref replication)
__device__ float g_rt[B * (V - 1) * 12];

// combine(): upd = K3 @ E[:3,:4]. XLA-CPU naive small-dot emitter semantics.
__device__ void combine_np(const float* __restrict__ proj, int b, int v, float Mo[4][4]) {
    const float* E = proj + ((size_t)(b * V + v) * 2 + 0) * 16;
    const float* K = proj + ((size_t)(b * V + v) * 2 + 1) * 16;
    for (int i = 0; i < 3; i++)
        for (int j = 0; j < 4; j++) {
            float acc = __fadd_rn(0.0f, __fmul_rn(K[i * 4 + 0], E[0 * 4 + j]));
            acc = __fadd_rn(acc, __fmul_rn(K[i * 4 + 1], E[1 * 4 + j]));
            acc = __fadd_rn(acc, __fmul_rn(K[i * 4 + 2], E[2 * 4 + j]));
            Mo[i][j] = acc;
        }
    for (int j = 0; j < 4; j++) Mo[3][j] = E[3 * 4 + j];
}

// ---------------------------------------------------------------------------
// Setup (unchanged, bit-exact strti2 + naive-emitter chains).
// ---------------------------------------------------------------------------
__global__ void setup_proj(const float* __restrict__ proj) {
    int t = threadIdx.x;
    if (t >= B * (V - 1)) return;
    int b = t / (V - 1);
    int v = t % (V - 1) + 1;

    float R[4][4], S[4][4];
    combine_np(proj, b, 0, R);
    combine_np(proj, b, v, S);

    float I4[4][4];
    for (int i = 0; i < 4; i++)
        for (int j = 0; j < 4; j++) I4[i][j] = 0.0f;

    float d0 = __fdiv_rn(1.0f, R[0][0]);
    I4[0][0] = d0;
    float d1 = __fdiv_rn(1.0f, R[1][1]);
    I4[1][1] = d1;
    {
        float x0 = R[0][1];
        if (x0 != 0.0f) x0 = __fmul_rn(x0, I4[0][0]);
        I4[0][1] = __fmul_rn(x0, -d1);
    }
    float d2 = __fdiv_rn(1.0f, R[2][2]);
    I4[2][2] = d2;
    {
        float x0 = R[0][2], x1 = R[1][2];
        if (x0 != 0.0f) x0 = __fmul_rn(x0, I4[0][0]);
        if (x1 != 0.0f) {
            x0 = __fadd_rn(x0, __fmul_rn(x1, I4[0][1]));
            x1 = __fmul_rn(x1, I4[1][1]);
        }
        I4[0][2] = __fmul_rn(x0, -d2);
        I4[1][2] = __fmul_rn(x1, -d2);
    }
    float d3 = __fdiv_rn(1.0f, R[3][3]);
    I4[3][3] = d3;
    {
        float x0 = R[0][3], x1 = R[1][3], x2 = R[2][3];
        if (x0 != 0.0f) x0 = __fmul_rn(x0, I4[0][0]);
        if (x1 != 0.0f) {
            x0 = __fadd_rn(x0, __fmul_rn(x1, I4[0][1]));
            x1 = __fmul_rn(x1, I4[1][1]);
        }
        if (x2 != 0.0f) {
            x0 = __fadd_rn(x0, __fmul_rn(x2, I4[0][2]));
            x1 = __fadd_rn(x1, __fmul_rn(x2, I4[1][2]));
            x2 = __fmul_rn(x2, I4[2][2]);
        }
        I4[0][3] = __fmul_rn(x0, -d3);
        I4[1][3] = __fmul_rn(x1, -d3);
        I4[2][3] = __fmul_rn(x2, -d3);
    }

    float P[3][4];
    for (int i = 0; i < 3; i++)
        for (int k = 0; k < 4; k++) {
            float acc = 0.0f;
            for (int j = 0; j < 4; j++)
                acc = __fadd_rn(acc, __fmul_rn(S[i][j], I4[j][k]));
            P[i][k] = acc;
        }

    float* out = g_rt + t * 12;
    out[0] = P[0][0]; out[1] = P[0][1]; out[2] = P[0][2];
    out[3] = P[1][0]; out[4] = P[1][1]; out[5] = P[1][2];
    out[6] = P[2][0]; out[7] = P[2][1]; out[8] = P[2][2];
    out[9] = P[0][3]; out[10] = P[1][3]; out[11] = P[2][3];
}

// ---------------------------------------------------------------------------
// R2 restructure: one thread per (b,h,w), ALL FOUR depth planes per thread.
// Evidence: R0 and R1 (very different structures) both pinned at 150us with
// identical L2-miss traffic (~396MB fetch vs 116MB compulsory) -> traffic-
// bound. Over-fetch is the d-partitioning: each src view (10.5MB >> 4MB
// per-XCD L2) was re-fetched once per depth plane. Adjacent-depth parallax
// is only ~4px, so one thread's 4 depth warps hit the SAME cache lines.
// Per c-iteration: 65 independent gathers (1 ref + 16 (v,d)-pairs x 4 taps),
// 4 nontemporal stores. Mask: per-thread popc over the 16 (v,d) any-channel-
// nonzero bits, direct store (atomic + memset dispatch removed).
// Chunked XCD swizzle: each XCD's resident blocks cover contiguous h rows,
// per-c working set ~400KB -> fits 4MB XCD L2.
// Numerics: identical op sequence per (v,d); per-(c,d) accumulation order
// unchanged (ref, then v=1..4 ascending) -> same bits as the passing R1.
// ---------------------------------------------------------------------------
__global__ __launch_bounds__(BLK, 2) void warp_var(
    const float* __restrict__ feats,
    const float* __restrict__ depthv,
    float* __restrict__ var_out,
    float* __restrict__ mask_out)
{
    // bijective chunked XCD swizzle (NBLK % 8 == 0)
    int bid = blockIdx.x;
    int bswz = (bid & 7) * (NBLK / 8) + (bid >> 3);
    int idx = bswz * BLK + threadIdx.x;

    int hw = idx % HW;
    int b = idx / HW;
    int w = hw % W;
    int h = hw / W;

    float dep[D];
#pragma unroll
    for (int d = 0; d < D; d++)
        dep[d] = depthv[(size_t)(b * D + d) * HW + hw];

    const float xf = (float)w, yf = (float)h;
    const float hwX = 0.5f * (float)(W - 1);  // 159.5
    const float hwY = 0.5f * (float)(H - 1);  // 127.5
    const float rcpX = 1.0f / 159.5f;  // fl(1/159.5), compile-time RN fold
    const float rcpY = 1.0f / 127.5f;  // fl(1/127.5)

    // Tap state per (v,d) pair p = (v-1)*4 + d: 4 element offsets (c=0 plane)
    // + 4 combined weights.
    int   toff[(V - 1) * D][4];
    float twt[(V - 1) * D][4];

#pragma unroll
    for (int v = 1; v < V; v++) {
        const float* P = g_rt + ((size_t)b * (V - 1) + (v - 1)) * 12;
        // rot_xyz is depth-independent: compute once per view (same ops/bits)
        float rx = __fadd_rn(__fmaf_rn(P[1], yf, __fmul_rn(P[0], xf)), P[2]);
        float ry = __fadd_rn(__fmaf_rn(P[4], yf, __fmul_rn(P[3], xf)), P[5]);
        float rz = __fadd_rn(__fmaf_rn(P[7], yf, __fmul_rn(P[6], xf)), P[8]);
        const int vb = (b * V + v) * C * HW;  // < 2^25, int32-safe
#pragma unroll
        for (int d = 0; d < D; d++) {
            const int p = (v - 1) * D + d;
            // pxyz = rot_xyz * depth + trans : two separate ops (no contract)
            float px = __fadd_rn(__fmul_rn(rx, dep[d]), P[9]);
            float py = __fadd_rn(__fmul_rn(ry, dep[d]), P[10]);
            float pz = __fadd_rn(__fmul_rn(rz, dep[d]), P[11]);
            float gx = __fdiv_rn(px, pz);
            float gy = __fdiv_rn(py, pz);
            // XLA: divide-by-constant -> multiply-by-folded-reciprocal
            float nx = __fadd_rn(__fmul_rn(gx, rcpX), -1.0f);
            float ny = __fadd_rn(__fmul_rn(gy, rcpY), -1.0f);
            float x = __fmul_rn(__fadd_rn(nx, 1.0f), hwX);
            float y = __fmul_rn(__fadd_rn(ny, 1.0f), hwY);

            float x0 = floorf(x), y0 = floorf(y);
            float x1 = x0 + 1.0f, y1 = y0 + 1.0f;

            float wx0 = __fadd_rn(1.0f, -fabsf(__fadd_rn(x, -x0)));
            float wx1 = __fadd_rn(1.0f, -fabsf(__fadd_rn(x, -x1)));
            float wy0 = __fadd_rn(1.0f, -fabsf(__fadd_rn(y, -y0)));
            float wy1 = __fadd_rn(1.0f, -fabsf(__fadd_rn(y, -y1)));

            float vx0 = (x0 >= 0.0f && x0 <= (float)(W - 1)) ? 1.0f : 0.0f;
            float vx1 = (x1 >= 0.0f && x1 <= (float)(W - 1)) ? 1.0f : 0.0f;
            float vy0 = (y0 >= 0.0f && y0 <= (float)(H - 1)) ? 1.0f : 0.0f;
            float vy1 = (y1 >= 0.0f && y1 <= (float)(H - 1)) ? 1.0f : 0.0f;

            twt[p][0] = __fmul_rn(__fmul_rn(wx0, wy0), __fmul_rn(vx0, vy0));
            twt[p][1] = __fmul_rn(__fmul_rn(wx1, wy0), __fmul_rn(vx1, vy0));
            twt[p][2] = __fmul_rn(__fmul_rn(wx0, wy1), __fmul_rn(vx0, vy1));
            twt[p][3] = __fmul_rn(__fmul_rn(wx1, wy1), __fmul_rn(vx1, vy1));

            int xi0 = (int)fminf(fmaxf(x0, 0.0f), (float)(W - 1));
            int xi1 = (int)fminf(fmaxf(x1, 0.0f), (float)(W - 1));
            int yi0 = (int)fminf(fmaxf(y0, 0.0f), (float)(H - 1));
            int yi1 = (int)fminf(fmaxf(y1, 0.0f), (float)(H - 1));

            toff[p][0] = vb + yi0 * W + xi0;
            toff[p][1] = vb + yi0 * W + xi1;
            toff[p][2] = vb + yi1 * W + xi0;
            toff[p][3] = vb + yi1 * W + xi1;
        }
    }

    const int rb = b * V * C * HW + hw;  // ref view, c=0 plane
    const float inv_v = 1.0f / (float)V;
    const size_t obase = (size_t)b * C * D * HW + (size_t)hw;

    int nzmask = 0;  // bit p set iff any channel of (v,d) pair p nonzero

    for (int c = 0; c < C; c++) {
        const int cofs = c * HW;
        // 65 independent gathers per iteration; 4 depths share cache lines.
        float rv = feats[rb + cofs];
        float s[D], q[D];
#pragma unroll
        for (int d = 0; d < D; d++) {
            s[d] = rv;
            q[d] = rv * rv;
        }
#pragma unroll
        for (int v = 0; v < V - 1; v++) {
#pragma unroll
            for (int d = 0; d < D; d++) {
                const int p = v * D + d;
                float f00 = feats[toff[p][0] + cofs];
                float f10 = feats[toff[p][1] + cofs];
                float f01 = feats[toff[p][2] + cofs];
                float f11 = feats[toff[p][3] + cofs];
                // zeroness is weight-structural (all-OOB => all wt exactly 0)
                float val = twt[p][0] * f00 + twt[p][1] * f10 + twt[p][2] * f01 + twt[p][3] * f11;
                nzmask |= (val != 0.0f) ? (1 << p) : 0;
                s[d] += val;
                q[d] += val * val;
            }
        }
        // variance = sq/V - (sum/V)^2 ; out layout [B,C,D,H,W]
#pragma unroll
        for (int d = 0; d < D; d++) {
            float sm = s[d] * inv_v;
            float vv = q[d] * inv_v - sm * sm;
            // streaming 86MB output: keep it out of the gather working set
            __builtin_nontemporal_store(
                vv, &var_out[obase + (size_t)c * (D * HW) + (size_t)d * HW]);
        }
    }

    // cv_mask[b,h,w] = sum_v #{d : any_c warped != 0} = popc(16-bit pair mask)
    mask_out[(size_t)b * HW + hw] = (float)__popc(nzmask);
}

extern "C" void kernel_launch(void* const* d_in, const int* in_sizes, int n_in,
                              void* d_out, int out_size, void* d_ws, size_t ws_size,
                              hipStream_t stream) {
    const float* feats = (const float*)d_in[0];
    const float* proj = (const float*)d_in[1];
    const float* depthv = (const float*)d_in[2];

    float* var = (float*)d_out;
    float* mask = var + (size_t)B * C * D * HW;

    setup_proj<<<1, 64, 0, stream>>>(proj);

    warp_var<<<NBLK, BLK, 0, stream>>>(feats, depthv, var, mask);
}